// Round 3
// baseline (791.799 us; speedup 1.0000x reference)
//
#include <hip/hip_runtime.h>
#include <hip/hip_bf16.h>

#define BB 256
#define DD 512
#define LL 32
#define HWN 196
#define TT 8
#define STEPB 12544   // bytes per packed K-step chunk: 8 kq * 196 cells * 8B

typedef __hip_bfloat16 bf16;
typedef __attribute__((ext_vector_type(8))) short short8;
typedef __attribute__((ext_vector_type(4))) float f32x4;

__device__ __forceinline__ float b2f(bf16 x) { return __bfloat162float(x); }
__device__ __forceinline__ unsigned short f2bu(float x) {
    bf16 h = __float2bfloat16(x);
    return *(unsigned short*)&h;
}
#define NEG_INF (-__builtin_huge_valf())

// ---- async global->LDS (wave-uniform LDS base + lane*size; global addr per-lane) ----
__device__ __forceinline__ void gload_lds16(const void* g, void* l) {
    __builtin_amdgcn_global_load_lds(
        (const __attribute__((address_space(1))) void*)g,
        (__attribute__((address_space(3))) void*)l, 16, 0, 0);
}
__device__ __forceinline__ void gload_lds4(const void* g, void* l) {
    __builtin_amdgcn_global_load_lds(
        (const __attribute__((address_space(1))) void*)g,
        (__attribute__((address_space(3))) void*)l, 4, 0, 0);
}

// ---------------- f32 -> bf16 weight convert (vectorized x4) ----------------
__global__ __launch_bounds__(256) void cvt_w_kernel(
    const float* __restrict__ src, unsigned short* __restrict__ dst, int n4)
{
    int i = blockIdx.x*256 + threadIdx.x;
    if (i < n4) {
        float4 f = ((const float4*)src)[i];
        ushort4 u;
        u.x = f2bu(f.x); u.y = f2bu(f.y); u.z = f2bu(f.z); u.w = f2bu(f.w);
        ((ushort4*)dst)[i] = u;
    }
}

// ---------------- pack f32 X[b][c][hw] -> MFMA-B-ready packed chunks ----------------
// Xp layout: [b][step][kq(8)][cell n(196)] ; cell = uint2 {k0|k1<<16, k2|k3<<16} bf16
// One step chunk = STEPB bytes = exactly what one conv K-step DMAs to LDS.
__global__ __launch_bounds__(256) void pack_x_kernel(
    const float* __restrict__ X, char* __restrict__ Xp)
{
    int b = blockIdx.x, s = blockIdx.y;
    uint2* chunk = (uint2*)(Xp + ((size_t)(b*16 + s))*STEPB);
    for (int idx = threadIdx.x; idx < 8*49; idx += 256) {
        int kq = idx / 49, n4 = idx % 49;
        const float* p = X + ((size_t)b*DD + s*32 + kq*4)*HWN + n4*4;
        ushort4 r[4];
        #pragma unroll
        for (int i = 0; i < 4; ++i) {
            float4 f = *(const float4*)(p + (size_t)i*HWN);
            r[i].x = f2bu(f.x); r[i].y = f2bu(f.y); r[i].z = f2bu(f.z); r[i].w = f2bu(f.w);
        }
        uint2* cell = chunk + kq*196 + n4*4;
        *(uint4*)(cell) = make_uint4(
            (uint)r[0].x | ((uint)r[1].x << 16), (uint)r[2].x | ((uint)r[3].x << 16),
            (uint)r[0].y | ((uint)r[1].y << 16), (uint)r[2].y | ((uint)r[3].y << 16));
        *(uint4*)(cell + 2) = make_uint4(
            (uint)r[0].z | ((uint)r[1].z << 16), (uint)r[2].z | ((uint)r[3].z << 16),
            (uint)r[0].w | ((uint)r[1].w << 16), (uint)r[2].w | ((uint)r[3].w << 16));
    }
}

// ---------------- small GEMM: out[b,d] = sum_k X[b,k]*W[d,k] + bias[d] ----------------
__global__ __launch_bounds__(256) void small_gemm_kernel(
    const float* __restrict__ A1, int K1,
    const float* __restrict__ A2, int K2,
    const float* __restrict__ Wt, const float* __restrict__ bias,
    float* __restrict__ outf, int Dout)
{
    __shared__ float xs[1024];
    int b = blockIdx.x, tid = threadIdx.x;
    int K = K1 + K2;
    for (int i = tid; i < K; i += 256) {
        xs[i] = (i < K1) ? A1[(size_t)b*K1 + i] : A2[(size_t)b*K2 + (i - K1)];
    }
    __syncthreads();
    for (int d = tid; d < Dout; d += 256) {
        const float4* wrow = (const float4*)(Wt + (size_t)d * K);
        float acc = 0.f;
        for (int j = 0; j < K/4; ++j) {
            float4 w = wrow[j];
            acc += w.x*xs[j*4] + w.y*xs[j*4+1] + w.z*xs[j*4+2] + w.w*xs[j*4+3];
        }
        if (bias) acc += bias[d];
        outf[(size_t)b*Dout + d] = acc;
    }
}

// ---------------- ControlUnit attention ----------------
__global__ __launch_bounds__(256) void control_kernel(
    const float* __restrict__ cq, const float* __restrict__ cw,
    const float* __restrict__ Wca, const float* __restrict__ bca,
    const int* __restrict__ mask,
    float* __restrict__ cnew_f, float* __restrict__ cv_out, float* __restrict__ cnew_out)
{
    __shared__ float u[DD];
    __shared__ float cas[LL];
    __shared__ float cvs[LL];
    int b = blockIdx.x, tid = threadIdx.x;
    for (int d = tid; d < DD; d += 256) u[d] = cq[(size_t)b*DD + d] * Wca[d];
    __syncthreads();
    int wave = tid >> 6, lane = tid & 63;
    float bca0 = bca[0];
    for (int lw = 0; lw < 8; ++lw) {
        int l = wave*8 + lw;
        const float4* w4 = (const float4*)(cw + ((size_t)(b*LL + l))*DD + lane*8);
        float4 wa = w4[0], wb = w4[1];
        const float* uu = &u[lane*8];
        float p = wa.x*uu[0] + wa.y*uu[1] + wa.z*uu[2] + wa.w*uu[3]
                + wb.x*uu[4] + wb.y*uu[5] + wb.z*uu[6] + wb.w*uu[7];
        for (int off = 32; off > 0; off >>= 1) p += __shfl_down(p, off);
        if (lane == 0) {
            float v = p + bca0;
            if (mask[b*LL + l] <= 0) v = NEG_INF;
            cas[l] = v;
        }
    }
    __syncthreads();
    if (tid < LL) {
        float mx = NEG_INF;
        for (int j = 0; j < LL; ++j) mx = fmaxf(mx, cas[j]);
        float s = 0.f;
        for (int j = 0; j < LL; ++j) s += __expf(cas[j] - mx);
        float cv = __expf(cas[tid] - mx) / s;
        cvs[tid] = cv;
        cv_out[b*LL + tid] = cv;
    }
    __syncthreads();
    for (int d = tid; d < DD; d += 256) {
        float acc = 0.f;
        for (int l = 0; l < LL; ++l) acc += cvs[l] * cw[((size_t)(b*LL + l))*DD + d];
        cnew_f[(size_t)b*DD + d] = acc;
        cnew_out[(size_t)b*DD + d] = acc;
    }
}

// ---------------- MFMA conv1x1 batched GEMM, DMA-staged ----------------
// Y[b,o,hw] = (sum_c W[o,c]*X[c,hw] + bias[o]) * (oscale ? oscale[b,o] : 1)
// X pre-packed (pack_x layout): staging = linear 12544B copy via 13 global_load_lds
// per block-step (zero staging VGPRs, ~13KB in flight per block -> fills the
// BW*latency product that the old reg-staged loop starved: 64B/wave in flight).
// LDS double-buffered; per step: barrier -> A-frag loads (first, so their vmcnt
// wait leaves the DMA queue outstanding) -> sched_barrier -> issue next-step DMA
// -> MFMA on current buffer. Barrier's vmcnt(0) drain = m97 pattern.
// Block: 512 thr = 8 waves (4wm x 2wn); wave = 2 mt x 7/6 nt of 16x16x32 MFMA.
__global__ __launch_bounds__(512) void conv_mfma_kernel(
    const char* __restrict__ X1p, int ns1,
    const char* __restrict__ X2p, int ns2,
    const unsigned short* __restrict__ Wb, int C,
    const float* __restrict__ bias, const float* __restrict__ oscale,
    void* __restrict__ Yout, int packed_out)
{
    // 12544 used + 256 pad per buffer (reads of pad cols n in 196..207 stay in-bounds)
    __shared__ __align__(16) char Xs[2][12800];
    int b = blockIdx.x, ot = blockIdx.y;
    int tid = threadIdx.x;
    int wave = tid >> 6, lane = tid & 63;
    int wm = wave >> 1, wn = wave & 1;
    int obase = ot*128 + wm*32;
    int n0 = wn*112;              // wn0: tiles 0..6 (n 0..111), wn1: tiles 0..5 (n 112..207)
    int ntn = wn ? 6 : 7;
    int ln = lane & 15, lq = lane >> 4;

    auto STAGE = [&](int s, char* lb) {
        const char* chunk = (s < ns1) ? X1p + ((size_t)b*ns1 + s)*STEPB
                                      : X2p + ((size_t)b*ns2 + (s - ns1))*STEPB;
        for (int i = wave; i < 13; i += 8) {
            if (i < 12) gload_lds16(chunk + i*1024 + lane*16, lb + i*1024);
            else        gload_lds4 (chunk + 12288 + lane*4,  lb + 12288);
        }
    };

    f32x4 acc[2][7];
    #pragma unroll
    for (int mt = 0; mt < 2; ++mt)
        #pragma unroll
        for (int nt = 0; nt < 7; ++nt) acc[mt][nt] = (f32x4){0.f, 0.f, 0.f, 0.f};

    STAGE(0, Xs[0]);
    int nsteps = ns1 + ns2;
    for (int s = 0; s < nsteps; ++s) {
        char* cur = Xs[s & 1];
        char* nxt = Xs[(s & 1) ^ 1];
        __syncthreads();   // drains vmcnt: cur is staged; buf^1 readers all done
        // A-frags first: their wait = vmcnt(<=2-deep), leaves next DMA outstanding
        short8 a0 = *(const short8*)(Wb + (size_t)(obase + ln)*C + s*32 + lq*8);
        short8 a1 = *(const short8*)(Wb + (size_t)(obase + 16 + ln)*C + s*32 + lq*8);
        __builtin_amdgcn_sched_barrier(0);
        if (s + 1 < nsteps) STAGE(s + 1, nxt);
        const uint2* cells = (const uint2*)cur;
        #pragma unroll
        for (int nt = 0; nt < 7; ++nt) {
            if (nt < ntn) {
                int n = n0 + nt*16 + ln;
                uint2 c0 = cells[(lq*2)*196 + n];
                uint2 c1 = cells[(lq*2 + 1)*196 + n];
                union { uint4 u; short8 s8; } bb;
                bb.u = make_uint4(c0.x, c0.y, c1.x, c1.y);
                acc[0][nt] = __builtin_amdgcn_mfma_f32_16x16x32_bf16(a0, bb.s8, acc[0][nt], 0, 0, 0);
                acc[1][nt] = __builtin_amdgcn_mfma_f32_16x16x32_bf16(a1, bb.s8, acc[1][nt], 0, 0, 0);
            }
        }
    }
    // ---- epilogue: C/D layout col = lane&15, row = (lane>>4)*4 + reg ----
    if (packed_out) {
        // write Y already in pack_x layout for the next conv in the chain
        uint2* Yp = (uint2*)Yout;
        #pragma unroll
        for (int mt = 0; mt < 2; ++mt) {
            int o4 = obase + mt*16 + lq*4;          // 4 consecutive o = this lane's rr 0..3
            int st = o4 >> 5, kqo = (o4 & 31) >> 2;
            float bo[4], os[4];
            #pragma unroll
            for (int rr = 0; rr < 4; ++rr) {
                bo[rr] = bias[o4 + rr];
                os[rr] = oscale ? oscale[(size_t)b*DD + o4 + rr] : 1.f;
            }
            #pragma unroll
            for (int nt = 0; nt < 7; ++nt) {
                int hw = n0 + nt*16 + ln;
                if (nt < ntn && hw < HWN) {
                    unsigned short v[4];
                    #pragma unroll
                    for (int rr = 0; rr < 4; ++rr)
                        v[rr] = f2bu((acc[mt][nt][rr] + bo[rr]) * os[rr]);
                    Yp[((size_t)(b*16 + st)*8 + kqo)*196 + hw] =
                        make_uint2((uint)v[0] | ((uint)v[1] << 16),
                                   (uint)v[2] | ((uint)v[3] << 16));
                }
            }
        }
    } else {
        unsigned short* Y = (unsigned short*)Yout;
        #pragma unroll
        for (int mt = 0; mt < 2; ++mt) {
            #pragma unroll
            for (int rr = 0; rr < 4; ++rr) {
                int o = obase + mt*16 + lq*4 + rr;
                float bo = bias[o];
                float os = oscale ? oscale[(size_t)b*DD + o] : 1.f;
                #pragma unroll
                for (int nt = 0; nt < 7; ++nt) {
                    int hw = n0 + nt*16 + ln;
                    if (nt < ntn && hw < HWN) {
                        float v = (acc[mt][nt][rr] + bo) * os;
                        Y[((size_t)b*DD + o)*HWN + hw] = f2bu(v);
                    }
                }
            }
        }
    }
}

// ---------------- channel softmax (512 c per (b,hw)) + r[b,c] = sum_hw rv*k ----------------
__global__ __launch_bounds__(512) void softmax_r_kernel(
    const bf16* __restrict__ ra, const float* __restrict__ kin,
    float* __restrict__ rv, float* __restrict__ r)
{
    __shared__ float pm[2][HWN], ps[2][HWN];
    __shared__ float mxs[HWN], sis[HWN];
    int b = blockIdx.x, tid = threadIdx.x;
    int half = tid >> 8, hw = tid & 255;
    if (hw < HWN) {
        float m = NEG_INF, s = 0.f;
        const bf16* base = ra + ((size_t)b*DD + half*256)*HWN + hw;
        for (int c = 0; c < 256; ++c) {
            float x = b2f(base[(size_t)c*HWN]);
            float nm = fmaxf(m, x);
            s = s*__expf(m - nm) + __expf(x - nm);
            m = nm;
        }
        pm[half][hw] = m; ps[half][hw] = s;
    }
    __syncthreads();
    if (tid < HWN) {
        float m0 = pm[0][tid], m1 = pm[1][tid];
        float m = fmaxf(m0, m1);
        float s = ps[0][tid]*__expf(m0 - m) + ps[1][tid]*__expf(m1 - m);
        mxs[tid] = m; sis[tid] = 1.f/s;
    }
    __syncthreads();
    int wave = tid >> 6, lane = tid & 63;
    for (int ci = 0; ci < 64; ++ci) {
        int c = wave*64 + ci;
        float psum = 0.f;
        #pragma unroll
        for (int g = 0; g < 4; ++g) {
            int hw2 = lane + 64*g;
            if (hw2 < HWN) {
                size_t idx = ((size_t)b*DD + c)*HWN + hw2;
                float e = __expf(b2f(ra[idx]) - mxs[hw2]) * sis[hw2];
                rv[idx] = e;
                psum += e * kin[idx];
            }
        }
        for (int off = 32; off > 0; off >>= 1) psum += __shfl_down(psum, off);
        if (lane == 0) r[(size_t)b*DD + c] = psum;
    }
}

// ---------------- sa softmax over T and m_sa (gate fused in) ----------------
__global__ __launch_bounds__(256) void samsa_kernel(
    const float* __restrict__ cs, const float* __restrict__ ms,
    const float* __restrict__ Wsa, const float* __restrict__ bsa,
    const float* __restrict__ cnew, const float* __restrict__ Wc, const float* __restrict__ bc,
    float* __restrict__ gate_out, float* __restrict__ msa)
{
    __shared__ float lg[TT];
    __shared__ float sas[TT];
    __shared__ float xw[DD];
    __shared__ float gsh;
    int b = blockIdx.x, tid = threadIdx.x;
    int wave = tid >> 6, lane = tid & 63;
    for (int d = tid; d < DD; d += 256) xw[d] = Wsa[d];
    __syncthreads();
    for (int tw = 0; tw < 2; ++tw) {
        int t = wave + 4*tw;
        const float4* c4 = (const float4*)(cs + ((size_t)t*BB + b)*DD + lane*8);
        float4 ca = c4[0], cb = c4[1];
        const float* ww = &xw[lane*8];
        float p = ca.x*ww[0] + ca.y*ww[1] + ca.z*ww[2] + ca.w*ww[3]
                + cb.x*ww[4] + cb.y*ww[5] + cb.z*ww[6] + cb.w*ww[7];
        for (int off = 32; off > 0; off >>= 1) p += __shfl_down(p, off);
        if (lane == 0) lg[t] = p;           // raw dot; gate applied after
    }
    if (wave == 0) {
        const float4* w4 = (const float4*)(Wc + lane*8);
        const float* x = &cnew[(size_t)b*DD + lane*8];
        float4 wa = w4[0], wb = w4[1];
        float p = wa.x*x[0] + wa.y*x[1] + wa.z*x[2] + wa.w*x[3]
                + wb.x*x[4] + wb.y*x[5] + wb.z*x[6] + wb.w*x[7];
        for (int off = 32; off > 0; off >>= 1) p += __shfl_down(p, off);
        if (lane == 0) {
            float g = 1.f / (1.f + __expf(-(p + bc[0])));
            gsh = g; gate_out[b] = g;
        }
    }
    __syncthreads();
    if (tid < TT) {
        float g = gsh, b0 = bsa[0];
        float mx = NEG_INF;
        for (int j = 0; j < TT; ++j) mx = fmaxf(mx, g*lg[j] + b0);
        float s = 0.f;
        for (int j = 0; j < TT; ++j) s += __expf(g*lg[j] + b0 - mx);
        sas[tid] = __expf(g*lg[tid] + b0 - mx) / s;
    }
    __syncthreads();
    for (int d = tid; d < DD; d += 256) {
        float acc = 0.f;
        for (int t = 0; t < TT; ++t) acc += sas[t] * ms[((size_t)t*BB + b)*DD + d];
        msa[(size_t)b*DD + d] = acc;
    }
}

// ---------------- m_new = g*m + (1-g)*(mund + msa@Ws^T)  (GEMM + final fused) ----------------
__global__ __launch_bounds__(256) void write_final_kernel(
    const float* __restrict__ msa, const float* __restrict__ Ws,
    const float* __restrict__ m, const float* __restrict__ gate,
    const float* __restrict__ mund, float* __restrict__ mnew)
{
    __shared__ float xs[DD];
    int b = blockIdx.x, tid = threadIdx.x;
    for (int i = tid; i < DD; i += 256) xs[i] = msa[(size_t)b*DD + i];
    __syncthreads();
    float g = gate[b];
    for (int d = tid; d < DD; d += 256) {
        const float4* wrow = (const float4*)(Ws + (size_t)d * DD);
        float acc = 0.f;
        for (int j = 0; j < DD/4; ++j) {
            float4 w = wrow[j];
            acc += w.x*xs[j*4] + w.y*xs[j*4+1] + w.z*xs[j*4+2] + w.w*xs[j*4+3];
        }
        size_t idx = (size_t)b*DD + d;
        mnew[idx] = g * m[idx] + (1.f - g) * (mund[idx] + acc);
    }
}

extern "C" void kernel_launch(void* const* d_in, const int* in_sizes, int n_in,
                              void* d_out, int out_size, void* d_ws, size_t ws_size,
                              hipStream_t stream)
{
    (void)in_sizes; (void)n_in; (void)out_size; (void)ws_size;
    const float* c    = (const float*)d_in[0];
    const float* m    = (const float*)d_in[1];
    const float* k    = (const float*)d_in[2];
    const float* q    = (const float*)d_in[3];
    const float* cw   = (const float*)d_in[4];
    const int*   mask = (const int*)  d_in[5];
    const float* cs   = (const float*)d_in[6];
    const float* ms   = (const float*)d_in[7];
    const float* Wcq  = (const float*)d_in[8];
    const float* bcq  = (const float*)d_in[9];
    const float* Wca  = (const float*)d_in[10];
    const float* bca  = (const float*)d_in[11];
    const float* Wm_r = (const float*)d_in[12];
    const float* bm_r = (const float*)d_in[13];
    const float* Wk   = (const float*)d_in[14];
    const float* bk   = (const float*)d_in[15];
    const float* WI   = (const float*)d_in[16];
    const float* bI   = (const float*)d_in[17];
    const float* Wra  = (const float*)d_in[18];
    const float* bra  = (const float*)d_in[19];
    const float* Wm_w = (const float*)d_in[20];
    const float* bm_w = (const float*)d_in[21];
    const float* Wsa  = (const float*)d_in[22];
    const float* bsa  = (const float*)d_in[23];
    const float* Wm2  = (const float*)d_in[24];
    const float* bm2  = (const float*)d_in[25];
    const float* Wc   = (const float*)d_in[26];
    const float* bc   = (const float*)d_in[27];
    const float* Ws   = (const float*)d_in[28];

    float* out_cnew = (float*)d_out;
    float* out_mnew = out_cnew + BB*DD;
    float* out_cv   = out_mnew + BB*DD;
    float* out_rv   = out_cv + BB*LL;     // 25,690,112 f32 = 102,760,448 B

    // d_out rv region doubles as packed bf16 scratch for Ip / I2p (dead before rv write)
    char* Ip  = (char*)out_rv;                       // 256*16*12544 = 51,380,224 B
    char* I2p = (char*)out_rv + 51380224;            // 51,380,224 B

    char* w = (char*)d_ws;                 // total footprint: 55,575,552 B (unchanged)
    float* s0      = (float*)(w + 0);        // cq -> r
    float* s1      = (float*)(w + 524288);   // cnew
    float* s2      = (float*)(w + 1048576);  // mI -> mund
    float* s3      = (float*)(w + 1572864);  // mprev -> msa
    unsigned short* Wkb  = (unsigned short*)(w + 2097152);   // 512x512 bf16
    unsigned short* WIb  = (unsigned short*)(w + 2621440);   // 512x1024 bf16
    unsigned short* Wrab = (unsigned short*)(w + 3670016);   // 512x512 bf16
    char* kp_ra = (char*)(w + 4194304);      // kp (packed k, 51,380,224B); ra overwrites after conv2
    float* gate_w  = (float*)(w + 55574528); // 1024 B

    float* cq_w   = s0;
    float* r_w    = s0;
    float* cnew_w = s1;
    float* mI_w   = s2;
    float* mund_w = s2;
    float* mprev_w= s3;
    float* msa_w  = s3;
    unsigned short* ra_w = (unsigned short*)kp_ra;   // conv3 output, standard [b][c][hw] bf16

    // Weight converts (f32 -> bf16), L2-resident thereafter
    cvt_w_kernel<<<256, 256, 0, stream>>>(Wk,  Wkb,  65536);
    cvt_w_kernel<<<512, 256, 0, stream>>>(WI,  WIb,  131072);
    cvt_w_kernel<<<256, 256, 0, stream>>>(Wra, Wrab, 65536);

    // Pack k once into MFMA-B layout (f32 103MB -> packed bf16 51MB)
    pack_x_kernel<<<dim3(BB, 16), 256, 0, stream>>>(k, kp_ra);

    // ControlUnit
    small_gemm_kernel<<<BB, 256, 0, stream>>>(c, DD, q, DD, Wcq, bcq, cq_w, DD);
    small_gemm_kernel<<<BB, 256, 0, stream>>>(m, DD, nullptr, 0, Wm_r, bm_r, mI_w, DD);
    control_kernel<<<BB, 256, 0, stream>>>(cq_w, cw, Wca, bca, mask, cnew_w, out_cv, out_cnew);

    // ReadUnit (MFMA convs): I = mI.(Wk k + bk); I2' = (WI [I;k] + bI).cnew; ra = Wra I2' + bra
    conv_mfma_kernel<<<dim3(BB, 4), 512, 0, stream>>>(kp_ra, 16, nullptr, 0,  Wkb,  DD,   bk,  mI_w,   Ip,   1);
    conv_mfma_kernel<<<dim3(BB, 4), 512, 0, stream>>>(Ip,    16, kp_ra,  16,  WIb,  2*DD, bI,  cnew_w, I2p,  1);
    conv_mfma_kernel<<<dim3(BB, 4), 512, 0, stream>>>(I2p,   16, nullptr, 0,  Wrab, DD,   bra, nullptr, ra_w, 0);
    softmax_r_kernel<<<BB, 512, 0, stream>>>((const bf16*)ra_w, k, out_rv, r_w);

    // WriteUnit
    small_gemm_kernel<<<BB, 256, 0, stream>>>(r_w, DD, m, DD, Wm_w, bm_w, mprev_w, DD);
    small_gemm_kernel<<<BB, 256, 0, stream>>>(mprev_w, DD, nullptr, 0, Wm2, bm2, mund_w, DD);
    samsa_kernel<<<BB, 256, 0, stream>>>(cs, ms, Wsa, bsa, cnew_w, Wc, bc, gate_w, msa_w);
    write_final_kernel<<<BB, 256, 0, stream>>>(msa_w, Ws, m, gate_w, mund_w, out_mnew);
}

// Round 4
// 783.105 us; speedup vs baseline: 1.0111x; 1.0111x over previous
//
#include <hip/hip_runtime.h>
#include <hip/hip_bf16.h>

#define BB 256
#define DD 512
#define LL 32
#define HWN 196
#define TT 8
#define STEPB 12544   // bytes per packed K-step chunk: 196 n-cells * 8 kq * 8B

typedef __hip_bfloat16 bf16;
typedef __attribute__((ext_vector_type(8))) short short8;
typedef __attribute__((ext_vector_type(4))) float f32x4;

__device__ __forceinline__ float b2f(bf16 x) { return __bfloat162float(x); }
__device__ __forceinline__ unsigned short f2bu(float x) {
    bf16 h = __float2bfloat16(x);
    return *(unsigned short*)&h;
}
#define NEG_INF (-__builtin_huge_valf())

// ---- async global->LDS (wave-uniform LDS base + lane*size; global addr per-lane) ----
__device__ __forceinline__ void gload_lds16(const void* g, void* l) {
    __builtin_amdgcn_global_load_lds(
        (const __attribute__((address_space(1))) void*)g,
        (__attribute__((address_space(3))) void*)l, 16, 0, 0);
}
__device__ __forceinline__ void gload_lds4(const void* g, void* l) {
    __builtin_amdgcn_global_load_lds(
        (const __attribute__((address_space(1))) void*)g,
        (__attribute__((address_space(3))) void*)l, 4, 0, 0);
}

// ---------------- f32 -> bf16 weight convert (vectorized x4) ----------------
__global__ __launch_bounds__(256) void cvt_w_kernel(
    const float* __restrict__ src, unsigned short* __restrict__ dst, int n4)
{
    int i = blockIdx.x*256 + threadIdx.x;
    if (i < n4) {
        float4 f = ((const float4*)src)[i];
        ushort4 u;
        u.x = f2bu(f.x); u.y = f2bu(f.y); u.z = f2bu(f.z); u.w = f2bu(f.w);
        ((ushort4*)dst)[i] = u;
    }
}

// ---------------- pack f32 X[b][c][hw] -> MFMA-B-ready packed chunks ----------------
// Chunk layout (NEW, [n][kq]): byte n*64 + kq*8; cell(n,kq) = uint2{c0|c1<<16, c2|c3<<16},
// cj = X[s*32 + kq*4 + j][n]. A lane's B-frag (k = lq*8..+7 at col n) is the 16
// contiguous bytes at n*64 + lq*16 -> single ds_read_b128, bank-uniform.
__global__ __launch_bounds__(256) void pack_x_kernel(
    const float* __restrict__ X, char* __restrict__ Xp)
{
    int b = blockIdx.x, s = blockIdx.y;
    char* chunk = Xp + ((size_t)(b*16 + s))*STEPB;
    for (int i = threadIdx.x; i < 4*HWN; i += 256) {
        int n = i >> 2, kqp = i & 3;          // kq pair: kq = 2*kqp, 2*kqp+1
        const float* base = X + ((size_t)b*DD + s*32 + kqp*8)*HWN + n;
        uint v[4];
        #pragma unroll
        for (int h = 0; h < 4; ++h) {
            float f0 = base[(size_t)(2*h+0)*HWN], f1 = base[(size_t)(2*h+1)*HWN];
            v[h] = (uint)f2bu(f0) | ((uint)f2bu(f1) << 16);
        }
        *(uint4*)(chunk + n*64 + kqp*16) = make_uint4(v[0], v[1], v[2], v[3]);
    }
}

// ---------------- small GEMM: out[b,d] = sum_k X[b,k]*W[d,k] + bias[d] ----------------
__global__ __launch_bounds__(256) void small_gemm_kernel(
    const float* __restrict__ A1, int K1,
    const float* __restrict__ A2, int K2,
    const float* __restrict__ Wt, const float* __restrict__ bias,
    float* __restrict__ outf, int Dout)
{
    __shared__ float xs[1024];
    int b = blockIdx.x, tid = threadIdx.x;
    int K = K1 + K2;
    for (int i = tid; i < K; i += 256) {
        xs[i] = (i < K1) ? A1[(size_t)b*K1 + i] : A2[(size_t)b*K2 + (i - K1)];
    }
    __syncthreads();
    for (int d = tid; d < Dout; d += 256) {
        const float4* wrow = (const float4*)(Wt + (size_t)d * K);
        float acc = 0.f;
        for (int j = 0; j < K/4; ++j) {
            float4 w = wrow[j];
            acc += w.x*xs[j*4] + w.y*xs[j*4+1] + w.z*xs[j*4+2] + w.w*xs[j*4+3];
        }
        if (bias) acc += bias[d];
        outf[(size_t)b*Dout + d] = acc;
    }
}

// ---------------- ControlUnit attention ----------------
__global__ __launch_bounds__(256) void control_kernel(
    const float* __restrict__ cq, const float* __restrict__ cw,
    const float* __restrict__ Wca, const float* __restrict__ bca,
    const int* __restrict__ mask,
    float* __restrict__ cnew_f, float* __restrict__ cv_out, float* __restrict__ cnew_out)
{
    __shared__ float u[DD];
    __shared__ float cas[LL];
    __shared__ float cvs[LL];
    int b = blockIdx.x, tid = threadIdx.x;
    for (int d = tid; d < DD; d += 256) u[d] = cq[(size_t)b*DD + d] * Wca[d];
    __syncthreads();
    int wave = tid >> 6, lane = tid & 63;
    float bca0 = bca[0];
    for (int lw = 0; lw < 8; ++lw) {
        int l = wave*8 + lw;
        const float4* w4 = (const float4*)(cw + ((size_t)(b*LL + l))*DD + lane*8);
        float4 wa = w4[0], wb = w4[1];
        const float* uu = &u[lane*8];
        float p = wa.x*uu[0] + wa.y*uu[1] + wa.z*uu[2] + wa.w*uu[3]
                + wb.x*uu[4] + wb.y*uu[5] + wb.z*uu[6] + wb.w*uu[7];
        for (int off = 32; off > 0; off >>= 1) p += __shfl_down(p, off);
        if (lane == 0) {
            float v = p + bca0;
            if (mask[b*LL + l] <= 0) v = NEG_INF;
            cas[l] = v;
        }
    }
    __syncthreads();
    if (tid < LL) {
        float mx = NEG_INF;
        for (int j = 0; j < LL; ++j) mx = fmaxf(mx, cas[j]);
        float s = 0.f;
        for (int j = 0; j < LL; ++j) s += __expf(cas[j] - mx);
        float cv = __expf(cas[tid] - mx) / s;
        cvs[tid] = cv;
        cv_out[b*LL + tid] = cv;
    }
    __syncthreads();
    for (int d = tid; d < DD; d += 256) {
        float acc = 0.f;
        for (int l = 0; l < LL; ++l) acc += cvs[l] * cw[((size_t)(b*LL + l))*DD + d];
        cnew_f[(size_t)b*DD + d] = acc;
        cnew_out[(size_t)b*DD + d] = acc;
    }
}

// ---------------- MFMA conv1x1 batched GEMM, 3-deep DMA pipeline ----------------
// Y[b,o,hw] = (sum_c W[o,c]*X[c,hw] + bias[o]) * (oscale ? oscale[b,o] : 1)
// K-loop (T4, counted vmcnt — never drain to 0 in steady state):
//   per iter s: s_waitcnt vmcnt(2)   (drains STAGE(s)+A(s); STAGE(s+1),STAGE(s+2) stay
//               in flight)  -> s_barrier -> issue A(s+1), STAGE(s+3) -> MFMA buf[s%4].
// Per-wave FIFO: batch = [A: 2 loads, X: <=2 gload_lds ops]; A-reg readiness is
// compiler-tracked (it counts the DMA ops too); the asm vmcnt guards DMA->ds_read.
// 4 LDS buffers x 12.8KB = 51.2KB -> 3 blocks/CU; in-flight ~25-37KB/block.
__global__ __launch_bounds__(512) void conv_mfma_kernel(
    const char* __restrict__ X1p, int ns1,
    const char* __restrict__ X2p, int ns2,
    const unsigned short* __restrict__ Wb, int C,
    const float* __restrict__ bias, const float* __restrict__ oscale,
    void* __restrict__ Yout, int packed_out)
{
    __shared__ __align__(16) char Xs[4][12800];
    int b = blockIdx.x, ot = blockIdx.y;
    int tid = threadIdx.x;
    int wave = tid >> 6, lane = tid & 63;
    int wm = wave >> 1, wn = wave & 1;
    int obase = ot*128 + wm*32;
    int n0 = wn*112;              // wn0: tiles 0..6 (n 0..111), wn1: tiles 0..5 (n 112..207)
    int ntn = wn ? 6 : 7;
    int ln = lane & 15, lq = lane >> 4;
    int nsteps = ns1 + ns2;

    auto STAGE = [&](int s) {
        const char* chunk = (s < ns1) ? X1p + ((size_t)b*ns1 + s)*STEPB
                                      : X2p + ((size_t)b*ns2 + (s - ns1))*STEPB;
        char* lb = Xs[s & 3];
        // 13 ops: waves 0-4 issue 2x 1KB; waves 5,6 1x 1KB; wave 7: 1KB + 256B tail
        gload_lds16(chunk + wave*1024 + lane*16, lb + wave*1024);
        if (wave < 5)       gload_lds16(chunk + (wave+8)*1024 + lane*16, lb + (wave+8)*1024);
        else if (wave == 7) gload_lds4 (chunk + 12288 + lane*4, lb + 12288);
    };
    auto ALOAD = [&](int s, short8& a0, short8& a1) {
        a0 = *(const short8*)(Wb + (size_t)(obase + ln)*C + s*32 + lq*8);
        a1 = *(const short8*)(Wb + (size_t)(obase + 16 + ln)*C + s*32 + lq*8);
    };

    f32x4 acc[2][7];
    #pragma unroll
    for (int mt = 0; mt < 2; ++mt)
        #pragma unroll
        for (int nt = 0; nt < 7; ++nt) acc[mt][nt] = (f32x4){0.f, 0.f, 0.f, 0.f};

    short8 a0c, a1c, a0n, a1n;

    // prologue: FIFO = [X0, X1, A0, X2]
    STAGE(0);
    STAGE(1);
    __builtin_amdgcn_sched_barrier(0);
    ALOAD(0, a0c, a1c);
    __builtin_amdgcn_sched_barrier(0);
    STAGE(2);

    auto BODY = [&](int s, bool doA, bool doX) {
        __builtin_amdgcn_s_barrier();
        if (doA) ALOAD(s + 1, a0n, a1n);
        __builtin_amdgcn_sched_barrier(0);
        if (doX) STAGE(s + 3);
        __builtin_amdgcn_sched_barrier(0);
        const char* curb = Xs[s & 3];
        #pragma unroll
        for (int nt = 0; nt < 7; ++nt) {
            if (nt < ntn) {
                int n = n0 + nt*16 + ln;
                union { uint4 u; short8 s8; } bb;
                bb.u = *(const uint4*)(curb + n*64 + lq*16);
                acc[0][nt] = __builtin_amdgcn_mfma_f32_16x16x32_bf16(a0c, bb.s8, acc[0][nt], 0, 0, 0);
                acc[1][nt] = __builtin_amdgcn_mfma_f32_16x16x32_bf16(a1c, bb.s8, acc[1][nt], 0, 0, 0);
            }
        }
        a0c = a0n; a1c = a1n;
    };

    for (int s = 0; s <= nsteps - 4; ++s) {
        asm volatile("s_waitcnt vmcnt(2)" ::: "memory");
        __builtin_amdgcn_sched_barrier(0);
        BODY(s, true, true);
    }
    {   // s = nsteps-3: STAGE(nsteps-1) already in flight; A(nsteps-2) still to load
        asm volatile("s_waitcnt vmcnt(2)" ::: "memory");
        __builtin_amdgcn_sched_barrier(0);
        BODY(nsteps - 3, true, false);
    }
    {   // s = nsteps-2
        asm volatile("s_waitcnt vmcnt(0)" ::: "memory");
        __builtin_amdgcn_sched_barrier(0);
        BODY(nsteps - 2, true, false);
    }
    {   // s = nsteps-1
        asm volatile("s_waitcnt vmcnt(0)" ::: "memory");
        __builtin_amdgcn_sched_barrier(0);
        BODY(nsteps - 1, false, false);
    }

    // ---- epilogue: C/D layout col = lane&15, row = (lane>>4)*4 + reg ----
    if (packed_out) {
        // write Y already in pack layout ([n][kq]) for the next conv in the chain
        uint2* Yp = (uint2*)Yout;
        #pragma unroll
        for (int mt = 0; mt < 2; ++mt) {
            int o4 = obase + mt*16 + lq*4;          // 4 consecutive o = this lane's rr 0..3
            int st = o4 >> 5, kqo = (o4 & 31) >> 2;
            uint2* chunk = Yp + (size_t)(b*16 + st)*1568;   // 1568 uint2 = STEPB
            float bo[4], os[4];
            #pragma unroll
            for (int rr = 0; rr < 4; ++rr) {
                bo[rr] = bias[o4 + rr];
                os[rr] = oscale ? oscale[(size_t)b*DD + o4 + rr] : 1.f;
            }
            #pragma unroll
            for (int nt = 0; nt < 7; ++nt) {
                int hw = n0 + nt*16 + ln;
                if (nt < ntn && hw < HWN) {
                    unsigned short v[4];
                    #pragma unroll
                    for (int rr = 0; rr < 4; ++rr)
                        v[rr] = f2bu((acc[mt][nt][rr] + bo[rr]) * os[rr]);
                    chunk[hw*8 + kqo] =
                        make_uint2((uint)v[0] | ((uint)v[1] << 16),
                                   (uint)v[2] | ((uint)v[3] << 16));
                }
            }
        }
    } else {
        unsigned short* Y = (unsigned short*)Yout;
        #pragma unroll
        for (int mt = 0; mt < 2; ++mt) {
            #pragma unroll
            for (int rr = 0; rr < 4; ++rr) {
                int o = obase + mt*16 + lq*4 + rr;
                float bo = bias[o];
                float os = oscale ? oscale[(size_t)b*DD + o] : 1.f;
                #pragma unroll
                for (int nt = 0; nt < 7; ++nt) {
                    int hw = n0 + nt*16 + ln;
                    if (nt < ntn && hw < HWN) {
                        float v = (acc[mt][nt][rr] + bo) * os;
                        Y[((size_t)b*DD + o)*HWN + hw] = f2bu(v);
                    }
                }
            }
        }
    }
}

// ---------------- channel softmax (512 c per (b,hw)) + r[b,c] = sum_hw rv*k ----------------
__global__ __launch_bounds__(512) void softmax_r_kernel(
    const bf16* __restrict__ ra, const float* __restrict__ kin,
    float* __restrict__ rv, float* __restrict__ r)
{
    __shared__ float pm[2][HWN], ps[2][HWN];
    __shared__ float mxs[HWN], sis[HWN];
    int b = blockIdx.x, tid = threadIdx.x;
    int half = tid >> 8, hw = tid & 255;
    if (hw < HWN) {
        float m = NEG_INF, s = 0.f;
        const bf16* base = ra + ((size_t)b*DD + half*256)*HWN + hw;
        for (int c = 0; c < 256; ++c) {
            float x = b2f(base[(size_t)c*HWN]);
            float nm = fmaxf(m, x);
            s = s*__expf(m - nm) + __expf(x - nm);
            m = nm;
        }
        pm[half][hw] = m; ps[half][hw] = s;
    }
    __syncthreads();
    if (tid < HWN) {
        float m0 = pm[0][tid], m1 = pm[1][tid];
        float m = fmaxf(m0, m1);
        float s = ps[0][tid]*__expf(m0 - m) + ps[1][tid]*__expf(m1 - m);
        mxs[tid] = m; sis[tid] = 1.f/s;
    }
    __syncthreads();
    int wave = tid >> 6, lane = tid & 63;
    for (int ci = 0; ci < 64; ++ci) {
        int c = wave*64 + ci;
        float psum = 0.f;
        #pragma unroll
        for (int g = 0; g < 4; ++g) {
            int hw2 = lane + 64*g;
            if (hw2 < HWN) {
                size_t idx = ((size_t)b*DD + c)*HWN + hw2;
                float e = __expf(b2f(ra[idx]) - mxs[hw2]) * sis[hw2];
                rv[idx] = e;
                psum += e * kin[idx];
            }
        }
        for (int off = 32; off > 0; off >>= 1) psum += __shfl_down(psum, off);
        if (lane == 0) r[(size_t)b*DD + c] = psum;
    }
}

// ---------------- sa softmax over T and m_sa (gate fused in) ----------------
__global__ __launch_bounds__(256) void samsa_kernel(
    const float* __restrict__ cs, const float* __restrict__ ms,
    const float* __restrict__ Wsa, const float* __restrict__ bsa,
    const float* __restrict__ cnew, const float* __restrict__ Wc, const float* __restrict__ bc,
    float* __restrict__ gate_out, float* __restrict__ msa)
{
    __shared__ float lg[TT];
    __shared__ float sas[TT];
    __shared__ float xw[DD];
    __shared__ float gsh;
    int b = blockIdx.x, tid = threadIdx.x;
    int wave = tid >> 6, lane = tid & 63;
    for (int d = tid; d < DD; d += 256) xw[d] = Wsa[d];
    __syncthreads();
    for (int tw = 0; tw < 2; ++tw) {
        int t = wave + 4*tw;
        const float4* c4 = (const float4*)(cs + ((size_t)t*BB + b)*DD + lane*8);
        float4 ca = c4[0], cb = c4[1];
        const float* ww = &xw[lane*8];
        float p = ca.x*ww[0] + ca.y*ww[1] + ca.z*ww[2] + ca.w*ww[3]
                + cb.x*ww[4] + cb.y*ww[5] + cb.z*ww[6] + cb.w*ww[7];
        for (int off = 32; off > 0; off >>= 1) p += __shfl_down(p, off);
        if (lane == 0) lg[t] = p;           // raw dot; gate applied after
    }
    if (wave == 0) {
        const float4* w4 = (const float4*)(Wc + lane*8);
        const float* x = &cnew[(size_t)b*DD + lane*8];
        float4 wa = w4[0], wb = w4[1];
        float p = wa.x*x[0] + wa.y*x[1] + wa.z*x[2] + wa.w*x[3]
                + wb.x*x[4] + wb.y*x[5] + wb.z*x[6] + wb.w*x[7];
        for (int off = 32; off > 0; off >>= 1) p += __shfl_down(p, off);
        if (lane == 0) {
            float g = 1.f / (1.f + __expf(-(p + bc[0])));
            gsh = g; gate_out[b] = g;
        }
    }
    __syncthreads();
    if (tid < TT) {
        float g = gsh, b0 = bsa[0];
        float mx = NEG_INF;
        for (int j = 0; j < TT; ++j) mx = fmaxf(mx, g*lg[j] + b0);
        float s = 0.f;
        for (int j = 0; j < TT; ++j) s += __expf(g*lg[j] + b0 - mx);
        sas[tid] = __expf(g*lg[tid] + b0 - mx) / s;
    }
    __syncthreads();
    for (int d = tid; d < DD; d += 256) {
        float acc = 0.f;
        for (int t = 0; t < TT; ++t) acc += sas[t] * ms[((size_t)t*BB + b)*DD + d];
        msa[(size_t)b*DD + d] = acc;
    }
}

// ---------------- m_new = g*m + (1-g)*(mund + msa@Ws^T)  (GEMM + final fused) ----------------
__global__ __launch_bounds__(256) void write_final_kernel(
    const float* __restrict__ msa, const float* __restrict__ Ws,
    const float* __restrict__ m, const float* __restrict__ gate,
    const float* __restrict__ mund, float* __restrict__ mnew)
{
    __shared__ float xs[DD];
    int b = blockIdx.x, tid = threadIdx.x;
    for (int i = tid; i < DD; i += 256) xs[i] = msa[(size_t)b*DD + i];
    __syncthreads();
    float g = gate[b];
    for (int d = tid; d < DD; d += 256) {
        const float4* wrow = (const float4*)(Ws + (size_t)d * DD);
        float acc = 0.f;
        for (int j = 0; j < DD/4; ++j) {
            float4 w = wrow[j];
            acc += w.x*xs[j*4] + w.y*xs[j*4+1] + w.z*xs[j*4+2] + w.w*xs[j*4+3];
        }
        size_t idx = (size_t)b*DD + d;
        mnew[idx] = g * m[idx] + (1.f - g) * (mund[idx] + acc);
    }
}

extern "C" void kernel_launch(void* const* d_in, const int* in_sizes, int n_in,
                              void* d_out, int out_size, void* d_ws, size_t ws_size,
                              hipStream_t stream)
{
    (void)in_sizes; (void)n_in; (void)out_size; (void)ws_size;
    const float* c    = (const float*)d_in[0];
    const float* m    = (const float*)d_in[1];
    const float* k    = (const float*)d_in[2];
    const float* q    = (const float*)d_in[3];
    const float* cw   = (const float*)d_in[4];
    const int*   mask = (const int*)  d_in[5];
    const float* cs   = (const float*)d_in[6];
    const float* ms   = (const float*)d_in[7];
    const float* Wcq  = (const float*)d_in[8];
    const float* bcq  = (const float*)d_in[9];
    const float* Wca  = (const float*)d_in[10];
    const float* bca  = (const float*)d_in[11];
    const float* Wm_r = (const float*)d_in[12];
    const float* bm_r = (const float*)d_in[13];
    const float* Wk   = (const float*)d_in[14];
    const float* bk   = (const float*)d_in[15];
    const float* WI   = (const float*)d_in[16];
    const float* bI   = (const float*)d_in[17];
    const float* Wra  = (const float*)d_in[18];
    const float* bra  = (const float*)d_in[19];
    const float* Wm_w = (const float*)d_in[20];
    const float* bm_w = (const float*)d_in[21];
    const float* Wsa  = (const float*)d_in[22];
    const float* bsa  = (const float*)d_in[23];
    const float* Wm2  = (const float*)d_in[24];
    const float* bm2  = (const float*)d_in[25];
    const float* Wc   = (const float*)d_in[26];
    const float* bc   = (const float*)d_in[27];
    const float* Ws   = (const float*)d_in[28];

    float* out_cnew = (float*)d_out;
    float* out_mnew = out_cnew + BB*DD;
    float* out_cv   = out_mnew + BB*DD;
    float* out_rv   = out_cv + BB*LL;     // 25,690,112 f32 = 102,760,448 B

    // d_out rv region doubles as packed bf16 scratch for Ip / I2p (dead before rv write)
    char* Ip  = (char*)out_rv;                       // 256*16*12544 = 51,380,224 B
    char* I2p = (char*)out_rv + 51380224;            // 51,380,224 B

    char* w = (char*)d_ws;                 // total footprint: 55,575,552 B (unchanged)
    float* s0      = (float*)(w + 0);        // cq -> r
    float* s1      = (float*)(w + 524288);   // cnew
    float* s2      = (float*)(w + 1048576);  // mI -> mund
    float* s3      = (float*)(w + 1572864);  // mprev -> msa
    unsigned short* Wkb  = (unsigned short*)(w + 2097152);   // 512x512 bf16
    unsigned short* WIb  = (unsigned short*)(w + 2621440);   // 512x1024 bf16
    unsigned short* Wrab = (unsigned short*)(w + 3670016);   // 512x512 bf16
    char* kp_ra = (char*)(w + 4194304);      // kp (packed k, 51,380,224B); ra overwrites after conv2
    float* gate_w  = (float*)(w + 55574528); // 1024 B

    float* cq_w   = s0;
    float* r_w    = s0;
    float* cnew_w = s1;
    float* mI_w   = s2;
    float* mund_w = s2;
    float* mprev_w= s3;
    float* msa_w  = s3;
    unsigned short* ra_w = (unsigned short*)kp_ra;   // conv3 output, standard [b][c][hw] bf16

    // Weight converts (f32 -> bf16), L2-resident thereafter
    cvt_w_kernel<<<256, 256, 0, stream>>>(Wk,  Wkb,  65536);
    cvt_w_kernel<<<512, 256, 0, stream>>>(WI,  WIb,  131072);
    cvt_w_kernel<<<256, 256, 0, stream>>>(Wra, Wrab, 65536);

    // Pack k once into MFMA-B layout (f32 103MB -> packed bf16 51MB)
    pack_x_kernel<<<dim3(BB, 16), 256, 0, stream>>>(k, kp_ra);

    // ControlUnit
    small_gemm_kernel<<<BB, 256, 0, stream>>>(c, DD, q, DD, Wcq, bcq, cq_w, DD);
    small_gemm_kernel<<<BB, 256, 0, stream>>>(m, DD, nullptr, 0, Wm_r, bm_r, mI_w, DD);
    control_kernel<<<BB, 256, 0, stream>>>(cq_w, cw, Wca, bca, mask, cnew_w, out_cv, out_cnew);

    // ReadUnit (MFMA convs): I = mI.(Wk k + bk); I2' = (WI [I;k] + bI).cnew; ra = Wra I2' + bra
    conv_mfma_kernel<<<dim3(BB, 4), 512, 0, stream>>>(kp_ra, 16, nullptr, 0,  Wkb,  DD,   bk,  mI_w,   Ip,   1);
    conv_mfma_kernel<<<dim3(BB, 4), 512, 0, stream>>>(Ip,    16, kp_ra,  16,  WIb,  2*DD, bI,  cnew_w, I2p,  1);
    conv_mfma_kernel<<<dim3(BB, 4), 512, 0, stream>>>(I2p,   16, nullptr, 0,  Wrab, DD,   bra, nullptr, ra_w, 0);
    softmax_r_kernel<<<BB, 512, 0, stream>>>((const bf16*)ra_w, k, out_rv, r_w);

    // WriteUnit
    small_gemm_kernel<<<BB, 256, 0, stream>>>(r_w, DD, m, DD, Wm_w, bm_w, mprev_w, DD);
    small_gemm_kernel<<<BB, 256, 0, stream>>>(mprev_w, DD, nullptr, 0, Wm2, bm2, mund_w, DD);
    samsa_kernel<<<BB, 256, 0, stream>>>(cs, ms, Wsa, bsa, cnew_w, Wc, bc, gate_w, msa_w);
    write_final_kernel<<<BB, 256, 0, stream>>>(msa_w, Ws, m, gate_w, mund_w, out_mnew);
}